// Round 14
// baseline (330.542 us; speedup 1.0000x reference)
//
#include <hip/hip_runtime.h>

#define D 128
#define OUTD 64
#define LAYERS 3
#define MAXBK 512   // max buckets (node>>7); N=50000 -> 391

typedef __attribute__((ext_vector_type(8))) short short8;
typedef __attribute__((ext_vector_type(4))) float float4v;
typedef __attribute__((ext_vector_type(2))) float floatx2;
typedef unsigned int uint32;

static inline int ceil_div(int a, int b) { return (a + b - 1) / b; }

__device__ __forceinline__ unsigned short f2bf(float f) {
    unsigned int u = __float_as_uint(f);
    unsigned int r = u + 0x7FFFu + ((u >> 16) & 1u);
    return (unsigned short)(r >> 16);
}

// feature permutation: storage element position of logical feature f.
__device__ __forceinline__ int fperm(int f) { return (f & 15) * 8 + (f >> 4); }

// packed-B slot for (input storage-pos fp, output n), RT = 8 (D out) or 4 (OUTD out).
// Per-(kc,nt) 1KB lane-major block: a wave's 64 lanes read 1KB contiguous (L2-hot).
__device__ __forceinline__ int bpack(int fp, int n, int RT) {
    int kc = fp >> 5, q = (fp >> 3) & 3, j = fp & 7;
    int nt = n >> 4, r16 = n & 15;
    return (kc * RT + nt) * 512 + (q * 16 + r16) * 8 + j;
}

// 8 fp8 bytes -> 8 bf16 (lossless: fp8->f32 exact, fp8 values exactly representable
// in bf16, so truncating f32->bf16 is exact).
__device__ __forceinline__ short8 fp8row_to_bf16(uint2 w) {
    floatx2 f01 = __builtin_amdgcn_cvt_pk_f32_fp8(w.x, false);
    floatx2 f23 = __builtin_amdgcn_cvt_pk_f32_fp8(w.x, true);
    floatx2 f45 = __builtin_amdgcn_cvt_pk_f32_fp8(w.y, false);
    floatx2 f67 = __builtin_amdgcn_cvt_pk_f32_fp8(w.y, true);
    uint32 p0 = (__float_as_uint(f01.x) >> 16) | (__float_as_uint(f01.y) & 0xFFFF0000u);
    uint32 p1 = (__float_as_uint(f23.x) >> 16) | (__float_as_uint(f23.y) & 0xFFFF0000u);
    uint32 p2 = (__float_as_uint(f45.x) >> 16) | (__float_as_uint(f45.y) & 0xFFFF0000u);
    uint32 p3 = (__float_as_uint(f67.x) >> 16) | (__float_as_uint(f67.y) & 0xFFFF0000u);
    uint4 u = make_uint4(p0, p1, p2, p3);
    return *(short8*)&u;
}

// ---------------- prep: bucket hist + LDS-staged x->bf16/fp8 + weight pack ----------------

#define BH_BLOCKS  64

__global__ __launch_bounds__(256)
void prep(const int* __restrict__ src, const int* __restrict__ dst, int E, int N, int NBK,
          int NCVX, int* bc,
          const float* __restrict__ x, short* __restrict__ hb, uint32* __restrict__ hq,
          const float* __restrict__ Wself, const float* __restrict__ Wstd,
          const float* __restrict__ Wdts, const float* __restrict__ Wlin,
          const float* __restrict__ bself, const float* __restrict__ bstd,
          const float* __restrict__ bdts, const float* __restrict__ alpha_p,
          short* __restrict__ wt, short* __restrict__ wlt, float* __restrict__ bcombp) {
    int b = blockIdx.x;
    if (b < BH_BLOCKS) {
        // combined per-bucket record counts (in + out records land in dest/src node buckets)
        __shared__ int bh[MAXBK];
        for (int i = threadIdx.x; i < MAXBK; i += 256) bh[i] = 0;
        __syncthreads();
        int per = (E + BH_BLOCKS - 1) / BH_BLOCKS;
        int lo = b * per, hi = min(E, lo + per);
        for (int e = lo + threadIdx.x; e < hi; e += 256) {
            int s = src[e], d = dst[e];
            atomicAdd(&bh[d >> 7], 1);
            atomicAdd(&bh[s >> 7], 1);
        }
        __syncthreads();
        for (int i = threadIdx.x; i < NBK; i += 256) {
            if (bh[i]) atomicAdd(&bc[i], bh[i]);
        }
    } else if (b < BH_BLOCKS + NCVX) {
        // LDS-staged convert: 32 nodes/block, coalesced float4 reads of x
        __shared__ float xs[32][132];
        int nb = (b - BH_BLOCKS) * 32;
        #pragma unroll
        for (int j = 0; j < 4; j++) {
            int f4 = threadIdx.x + j * 256;      // 0..1023 float4 slots
            int row = f4 >> 5, c4 = f4 & 31;
            float4 v = make_float4(0.f, 0.f, 0.f, 0.f);
            if (nb + row < N) v = *(const float4*)(x + (size_t)(nb + row) * D + c4 * 4);
            *(float4*)&xs[row][c4 * 4] = v;
        }
        __syncthreads();
        #pragma unroll
        for (int j = 0; j < 2; j++) {
            int ch = threadIdx.x + j * 256;      // 0..511 (node, q) chunks
            int r = ch >> 4, q = ch & 15;
            int n = nb + r;
            if (n < N) {
                float v[8];
                short8 s;
                #pragma unroll
                for (int fh = 0; fh < 8; fh++) {
                    float f = xs[r][q + fh * 16];
                    v[fh] = f;
                    s[fh] = (short)f2bf(f);
                }
                *(short8*)(hb + (size_t)n * D + q * 8) = s;
                uint32 u0 = __builtin_amdgcn_cvt_pk_fp8_f32(v[0], v[1], 0, false);
                u0 = __builtin_amdgcn_cvt_pk_fp8_f32(v[2], v[3], u0, true);
                uint32 u1 = __builtin_amdgcn_cvt_pk_fp8_f32(v[4], v[5], 0, false);
                u1 = __builtin_amdgcn_cvt_pk_fp8_f32(v[6], v[7], u1, true);
                *(uint2*)((char*)hq + (size_t)n * 128 + q * 8) = make_uint2(u0, u1);
            }
        }
    } else {
        int cb = b - BH_BLOCKS - NCVX;   // 0..10
        if (cb < 9) {
            int l = cb / 3, m = cb % 3;
            float a = alpha_p[0];
            float sc = (m == 0) ? 1.0f : ((m == 1) ? (1.0f - a) : a);
            const float* W = (m == 0 ? Wself : (m == 1 ? Wstd : Wdts)) + (size_t)l * D * D;
            short* o = wt + (size_t)cb * D * D;
            for (int idx = threadIdx.x; idx < D * D; idx += 256) {
                int k = idx >> 7, n = idx & 127;   // W[k][n]: input k -> output n
                o[bpack(fperm(k), n, 8)] = (short)f2bf(W[idx] * sc);
            }
        } else if (cb == 9) {
            for (int idx = threadIdx.x; idx < D * OUTD; idx += 256) {
                int k = idx >> 6, n = idx & 63;
                wlt[bpack(fperm(k), n, 4)] = (short)f2bf(Wlin[idx]);
            }
        } else {
            float a = alpha_p[0];
            for (int i = threadIdx.x; i < LAYERS * D; i += 256) {
                int l = i >> 7, j = i & 127;
                bcombp[l * D + fperm(j)] = bself[i] + (1.0f - a) * bstd[i] + a * bdts[i];
            }
        }
    }
}

// ---------------- scan over NBK buckets ----------------

__global__ __launch_bounds__(1024)
void scan1(const int* __restrict__ bc, int* __restrict__ off, int* __restrict__ bcur, int n) {
    __shared__ int wsum[16];
    __shared__ int total;
    int tid = threadIdx.x, lane = tid & 63, w = tid >> 6;
    int v = (tid < n) ? bc[tid] : 0;
    int x = v;
    #pragma unroll
    for (int o = 1; o < 64; o <<= 1) {
        int y = __shfl_up(x, o, 64);
        if (lane >= o) x += y;
    }
    if (lane == 63) wsum[w] = x;
    __syncthreads();
    if (w == 0 && lane < 16) {
        int s = wsum[lane];
        #pragma unroll
        for (int o = 1; o < 16; o <<= 1) {
            int y = __shfl_up(s, o, 16);
            if (lane >= o) s += y;
        }
        wsum[lane] = s;
        if (lane == 15) total = s;
    }
    __syncthreads();
    int wpre = w ? wsum[w - 1] : 0;
    if (tid < n) {
        int e = wpre + x - v;
        off[tid] = e;
        bcur[tid] = e;
    }
    if (tid == 0) off[n] = total;
}

// ---------------- build: binned edge append (combined records) ----------------
// record = payload << 7 | (node & 127); payload = src (in-edge) or dst + N (out-edge).

#define AP_BLOCKS 128

__global__ __launch_bounds__(256)
void build(const int* __restrict__ src, const int* __restrict__ dst, int E, int N,
           int NBK, int* bcur, uint32* __restrict__ ebuf) {
    __shared__ int h[MAXBK];
    int b = blockIdx.x;
    for (int i = threadIdx.x; i < MAXBK; i += 256) h[i] = 0;
    __syncthreads();
    int per = (E + AP_BLOCKS - 1) / AP_BLOCKS;
    int lo = b * per, hi = min(E, lo + per);
    for (int e = lo + threadIdx.x; e < hi; e += 256) {
        int s = src[e], d = dst[e];
        atomicAdd(&h[d >> 7], 1);
        atomicAdd(&h[s >> 7], 1);
    }
    __syncthreads();
    for (int i = threadIdx.x; i < NBK; i += 256) {
        int c = h[i];
        h[i] = c ? atomicAdd(&bcur[i], c) : 0;
    }
    __syncthreads();
    for (int e = lo + threadIdx.x; e < hi; e += 256) {
        int s = src[e], d = dst[e];
        int p = atomicAdd(&h[d >> 7], 1);
        ebuf[p] = ((uint32)s << 7) | (uint32)(d & 127);
        int q = atomicAdd(&h[s >> 7], 1);
        ebuf[q] = ((uint32)(d + N) << 7) | (uint32)(s & 127);
    }
}

// ---------------- bucket_count_fill ----------------
// rowx[2n] = in start, rowx[2n+1] = out start, rowx[2n+2] = end.
// col stores BYTE OFFSETS (node * 128) into the single fp8 table hq.

__global__ __launch_bounds__(256)
void bucket_count_fill(const uint32* __restrict__ ebuf, const int* __restrict__ off,
                       int* __restrict__ rowx, int* __restrict__ col, int N, int NBK) {
    __shared__ int cnt[256];
    __shared__ int wsum4[4];
    __shared__ int lcur[256];
    int k = blockIdx.x;
    int nb = k << 7;
    int tid = threadIdx.x;
    cnt[tid] = 0;
    __syncthreads();
    int lo = off[k], hi = off[k + 1];
    for (int r = lo + tid; r < hi; r += 256) {
        uint32 rec = ebuf[r];
        int t = ((rec >> 7) >= (uint32)N) ? 1 : 0;
        atomicAdd(&cnt[((rec & 127u) << 1) | t], 1);
    }
    __syncthreads();
    int lane = tid & 63, w = tid >> 6;
    int v = cnt[tid];
    int x = v;
    #pragma unroll
    for (int o = 1; o < 64; o <<= 1) {
        int y = __shfl_up(x, o, 64);
        if (lane >= o) x += y;
    }
    if (lane == 63) wsum4[w] = x;
    __syncthreads();
    if (tid == 0) {
        int s = 0;
        #pragma unroll
        for (int i = 0; i < 4; i++) { int t = wsum4[i]; wsum4[i] = s; s += t; }
    }
    __syncthreads();
    int excl = lo + wsum4[w] + x - v;
    int node = nb + (tid >> 1);
    if (node < N) rowx[(node << 1) | (tid & 1)] = excl;
    lcur[tid] = excl;
    if (k == NBK - 1 && tid == 0) rowx[2 * N] = hi;
    __syncthreads();
    for (int r = lo + tid; r < hi; r += 256) {
        uint32 rec = ebuf[r];
        uint32 pay = rec >> 7;
        int t = (pay >= (uint32)N) ? 1 : 0;
        int slot = atomicAdd(&lcur[((rec & 127u) << 1) | t], 1);
        col[slot] = (int)(((pay >= (uint32)N) ? (pay - (uint32)N) : pay) << 7);
    }
}

// ---------------- agg4: 2 nodes/wave, 4 lockstep record streams ----------------
// Streams: {n0-in, n0-out, n1-in, n1-out}, iterated together: 8 col loads + 8
// gathers issue per iteration before any wait. Clamped col addressing (provably
// in-bounds); tail lanes gather the zero row. After xor-16/32 reduction every
// lane holds the full sum: lane>>4 selects which of the 4 outputs it writes.
// Outputs are fp8 rows (AinQ/AoutQ, 128B/node) - halves agg write + gemm read.

__global__ __launch_bounds__(256)
void agg4(const uint32* __restrict__ hq,
          const int* __restrict__ rowx, const int* __restrict__ col,
          uint32* __restrict__ AinQ, uint32* __restrict__ AoutQ, int N) {
    int wv = threadIdx.x >> 6;
    int lane = threadIdx.x & 63;
    int n0 = (blockIdx.x * 4 + wv) * 2;
    if (n0 >= N) return;
    int n1 = n0 + 1;
    int has1 = (n1 < N) ? 1 : 0;

    int4 rx = *(const int4*)(rowx + 2 * n0);   // n0 even -> 16B aligned
    int l0 = rx.x, h0 = rx.y;                  // n0 in
    int l1 = rx.y, h1 = rx.z;                  // n0 out
    int l2 = 0, h2 = 0, l3 = 0, h3 = 0;
    if (has1) { l2 = rx.z; h2 = rx.w; l3 = rx.w; h3 = rowx[2 * n0 + 4]; }

    int rgrp = lane >> 4;
    int c8 = (lane & 15) * 8;
    int ZRB = N * 128;                         // byte offset of zero row
    const char* tb = (const char*)hq;

    floatx2 A0[4], A1[4], A2[4], A3[4];        // per-stream accumulators
    #pragma unroll
    for (int j = 0; j < 4; j++) {
        A0[j] = (floatx2){0.f, 0.f};
        A1[j] = (floatx2){0.f, 0.f};
        A2[j] = (floatx2){0.f, 0.f};
        A3[j] = (floatx2){0.f, 0.f};
    }

    int len = max(max(h0 - l0, h1 - l1), max(h2 - l2, h3 - l3));
    for (int q = 0; q < len; q += 8) {
        int ea0 = l0 + q + rgrp, eb0 = ea0 + 4;
        int ea1 = l1 + q + rgrp, eb1 = ea1 + 4;
        int ea2 = l2 + q + rgrp, eb2 = ea2 + 4;
        int ea3 = l3 + q + rgrp, eb3 = ea3 + 4;
        // 8 col loads (clamped addresses: always in-bounds)
        int ca0 = col[(ea0 < h0) ? ea0 : l0];
        int cb0 = col[(eb0 < h0) ? eb0 : l0];
        int ca1 = col[(ea1 < h1) ? ea1 : l1];
        int cb1 = col[(eb1 < h1) ? eb1 : l1];
        int ca2 = col[(ea2 < h2) ? ea2 : l2];
        int cb2 = col[(eb2 < h2) ? eb2 : l2];
        int ca3 = col[(ea3 < h3) ? ea3 : l3];
        int cb3 = col[(eb3 < h3) ? eb3 : l3];
        ca0 = (ea0 < h0) ? ca0 : ZRB;  cb0 = (eb0 < h0) ? cb0 : ZRB;
        ca1 = (ea1 < h1) ? ca1 : ZRB;  cb1 = (eb1 < h1) ? cb1 : ZRB;
        ca2 = (ea2 < h2) ? ca2 : ZRB;  cb2 = (eb2 < h2) ? cb2 : ZRB;
        ca3 = (ea3 < h3) ? ca3 : ZRB;  cb3 = (eb3 < h3) ? cb3 : ZRB;
        // 8 gathers
        uint2 va0 = *(const uint2*)(tb + (ca0 + c8));
        uint2 vb0 = *(const uint2*)(tb + (cb0 + c8));
        uint2 va1 = *(const uint2*)(tb + (ca1 + c8));
        uint2 vb1 = *(const uint2*)(tb + (cb1 + c8));
        uint2 va2 = *(const uint2*)(tb + (ca2 + c8));
        uint2 vb2 = *(const uint2*)(tb + (cb2 + c8));
        uint2 va3 = *(const uint2*)(tb + (ca3 + c8));
        uint2 vb3 = *(const uint2*)(tb + (cb3 + c8));
        #define ACCUM(ACC, va, vb) \
            ACC[0] += __builtin_amdgcn_cvt_pk_f32_fp8(va.x, false); \
            ACC[1] += __builtin_amdgcn_cvt_pk_f32_fp8(va.x, true);  \
            ACC[2] += __builtin_amdgcn_cvt_pk_f32_fp8(va.y, false); \
            ACC[3] += __builtin_amdgcn_cvt_pk_f32_fp8(va.y, true);  \
            ACC[0] += __builtin_amdgcn_cvt_pk_f32_fp8(vb.x, false); \
            ACC[1] += __builtin_amdgcn_cvt_pk_f32_fp8(vb.x, true);  \
            ACC[2] += __builtin_amdgcn_cvt_pk_f32_fp8(vb.y, false); \
            ACC[3] += __builtin_amdgcn_cvt_pk_f32_fp8(vb.y, true);
        ACCUM(A0, va0, vb0)
        ACCUM(A1, va1, vb1)
        ACCUM(A2, va2, vb2)
        ACCUM(A3, va3, vb3)
        #undef ACCUM
    }

    // fold in per-stream 1/deg, then reduce across row-groups
    float s0 = 1.0f / (float)max(h0 - l0, 1);
    float s1 = 1.0f / (float)max(h1 - l1, 1);
    float s2 = 1.0f / (float)max(h2 - l2, 1);
    float s3 = 1.0f / (float)max(h3 - l3, 1);
    floatx2 w0 = {s0, s0}, w1 = {s1, s1}, w2 = {s2, s2}, w3 = {s3, s3};
    #pragma unroll
    for (int j = 0; j < 4; j++) {
        A0[j] = A0[j] * w0;
        A1[j] = A1[j] * w1;
        A2[j] = A2[j] * w2;
        A3[j] = A3[j] * w3;
    }

    #define RED(X) \
        X.x += __shfl_xor(X.x, 16, 64); X.y += __shfl_xor(X.y, 16, 64); \
        X.x += __shfl_xor(X.x, 32, 64); X.y += __shfl_xor(X.y, 32, 64);
    #pragma unroll
    for (int j = 0; j < 4; j++) { RED(A0[j]) RED(A1[j]) RED(A2[j]) RED(A3[j]) }
    #undef RED

    // lane g = lane>>4 writes stream g: 0 -> AinQ[n0], 1 -> AoutQ[n0], 2 -> AinQ[n1], 3 -> AoutQ[n1]
    int g = lane >> 4;
    if (g < 2 || has1) {
        floatx2 S0 = (g == 0) ? A0[0] : ((g == 1) ? A1[0] : ((g == 2) ? A2[0] : A3[0]));
        floatx2 S1 = (g == 0) ? A0[1] : ((g == 1) ? A1[1] : ((g == 2) ? A2[1] : A3[1]));
        floatx2 S2 = (g == 0) ? A0[2] : ((g == 1) ? A1[2] : ((g == 2) ? A2[2] : A3[2]));
        floatx2 S3 = (g == 0) ? A0[3] : ((g == 1) ? A1[3] : ((g == 2) ? A2[3] : A3[3]));
        uint32 u0 = __builtin_amdgcn_cvt_pk_fp8_f32(S0.x, S0.y, 0, false);
        u0 = __builtin_amdgcn_cvt_pk_fp8_f32(S1.x, S1.y, u0, true);
        uint32 u1 = __builtin_amdgcn_cvt_pk_fp8_f32(S2.x, S2.y, 0, false);
        u1 = __builtin_amdgcn_cvt_pk_fp8_f32(S3.x, S3.y, u1, true);
        int node = (g & 2) ? n1 : n0;
        char* dp = (char*)((g & 1) ? AoutQ : AinQ) + (size_t)node * 128 + c8;
        *(uint2*)dp = make_uint2(u0, u1);
    }
}

// ---------------- gemm_sum: hout = relu(hin@Wself + Ain@Wstd' + Aout@Wdts' + b) ----------------
// 128-node tile, 4 waves x 32 rows. Self A from bf16 hin; aggregate A from fp8 rows
// (lossless fp8->bf16 in-register). B packed global (bpack layout, L2-hot).
// Writes hout (bf16, per-layer buffer) + hq (fp8 table).

__global__ __launch_bounds__(256)
void gemm_sum(const short* __restrict__ hin,
              const uint32* __restrict__ AinQ, const uint32* __restrict__ AoutQ,
              const short* __restrict__ wtp, const float* __restrict__ bcombp,
              short* __restrict__ hout, uint32* __restrict__ hq, int N) {
    int tid = threadIdx.x;
    int wave = tid >> 6, lane = tid & 63;
    int quad = lane >> 4, r16 = lane & 15;
    int m0 = blockIdx.x * 128, mrow = wave * 32;
    int gr0 = m0 + mrow + r16, gr1 = gr0 + 16;

    float4v acc[2][8];
    #pragma unroll
    for (int a = 0; a < 2; a++)
        #pragma unroll
        for (int b = 0; b < 8; b++)
            acc[a][b] = (float4v){0.f, 0.f, 0.f, 0.f};

    // z = 0: self term (bf16 A)
    #pragma unroll
    for (int kc = 0; kc < 4; kc++) {
        short8 a0 = {0, 0, 0, 0, 0, 0, 0, 0};
        short8 a1 = {0, 0, 0, 0, 0, 0, 0, 0};
        if (gr0 < N) a0 = *(const short8*)(hin + (size_t)gr0 * D + kc * 32 + quad * 8);
        if (gr1 < N) a1 = *(const short8*)(hin + (size_t)gr1 * D + kc * 32 + quad * 8);
        #pragma unroll
        for (int nt = 0; nt < 8; nt++) {
            short8 b = *(const short8*)(wtp + ((kc * 8 + nt) * 64 + lane) * 8);
            acc[0][nt] = __builtin_amdgcn_mfma_f32_16x16x32_bf16(a0, b, acc[0][nt], 0, 0, 0);
            acc[1][nt] = __builtin_amdgcn_mfma_f32_16x16x32_bf16(a1, b, acc[1][nt], 0, 0, 0);
        }
    }
    // z = 1,2: aggregate terms (fp8 A -> bf16, lossless)
    for (int z = 1; z < 3; z++) {
        const char* Aq = (const char*)((z == 1) ? AinQ : AoutQ);
        const short* Bz = wtp + (size_t)z * D * D;
        #pragma unroll
        for (int kc = 0; kc < 4; kc++) {
            short8 a0 = {0, 0, 0, 0, 0, 0, 0, 0};
            short8 a1 = {0, 0, 0, 0, 0, 0, 0, 0};
            if (gr0 < N) a0 = fp8row_to_bf16(*(const uint2*)(Aq + (size_t)gr0 * 128 + kc * 32 + quad * 8));
            if (gr1 < N) a1 = fp8row_to_bf16(*(const uint2*)(Aq + (size_t)gr1 * 128 + kc * 32 + quad * 8));
            #pragma unroll
            for (int nt = 0; nt < 8; nt++) {
                short8 b = *(const short8*)(Bz + ((kc * 8 + nt) * 64 + lane) * 8);
                acc[0][nt] = __builtin_amdgcn_mfma_f32_16x16x32_bf16(a0, b, acc[0][nt], 0, 0, 0);
                acc[1][nt] = __builtin_amdgcn_mfma_f32_16x16x32_bf16(a1, b, acc[1][nt], 0, 0, 0);
            }
        }
    }

    float4 bA = *(const float4*)(bcombp + r16 * 8);
    float4 bB = *(const float4*)(bcombp + r16 * 8 + 4);
    float bias[8] = {bA.x, bA.y, bA.z, bA.w, bB.x, bB.y, bB.z, bB.w};

    #pragma unroll
    for (int rt = 0; rt < 2; rt++)
        #pragma unroll
        for (int reg = 0; reg < 4; reg++) {
            int row = m0 + mrow + rt * 16 + quad * 4 + reg;
            if (row >= N) continue;
            float h[8];
            short8 s8;
            #pragma unroll
            for (int nt = 0; nt < 8; nt++) {
                h[nt] = fmaxf(acc[rt][nt][reg] + bias[nt], 0.f);
                s8[nt] = (short)f2bf(h[nt]);
            }
            *(short8*)(hout + (size_t)row * D + r16 * 8) = s8;
            uint32 u0 = __builtin_amdgcn_cvt_pk_fp8_f32(h[0], h[1], 0, false);
            u0 = __builtin_amdgcn_cvt_pk_fp8_f32(h[2], h[3], u0, true);
            uint32 u1 = __builtin_amdgcn_cvt_pk_fp8_f32(h[4], h[5], 0, false);
            u1 = __builtin_amdgcn_cvt_pk_fp8_f32(h[6], h[7], u1, true);
            *(uint2*)((char*)hq + (size_t)row * 128 + r16 * 8) = make_uint2(u0, u1);
        }
}

// ---------------- gemm_last: layer-2 sum-GEMM + relu + 3-way JK-max + output GEMM ----------------
// JK = max(h1, h2, h3): h3 computed in-register; h1 read from its buffer; h2 = hin
// (same buffer as the A-operand reads -> L1/L2-hot re-read, ~no extra HBM).

__global__ __launch_bounds__(256)
void gemm_last(const short* __restrict__ hin,          // h2 state (layer-2 input)
               const uint32* __restrict__ AinQ, const uint32* __restrict__ AoutQ,
               const short* __restrict__ wtp, const float* __restrict__ bcombp,
               const short* __restrict__ h1b,          // h1 buffer
               const short* __restrict__ wltp, const float* __restrict__ blin,
               float* __restrict__ Cout, int N) {
    __shared__ __align__(16) short Js[128 * 136];
    int tid = threadIdx.x;
    int wave = tid >> 6, lane = tid & 63;
    int quad = lane >> 4, r16 = lane & 15;
    int m0 = blockIdx.x * 128, mrow = wave * 32;
    int gr0 = m0 + mrow + r16, gr1 = gr0 + 16;

    float4v acc[2][8];
    #pragma unroll
    for (int a = 0; a < 2; a++)
        #pragma unroll
        for (int b = 0; b < 8; b++)
            acc[a][b] = (float4v){0.f, 0.f, 0.f, 0.f};

    // z = 0: self term (bf16 A)
    #pragma unroll
    for (int kc = 0; kc < 4; kc++) {
        short8 a0 = {0, 0, 0, 0, 0, 0, 0, 0};
        short8 a1 = {0, 0, 0, 0, 0, 0, 0, 0};
        if (gr0 < N) a0 = *(const short8*)(hin + (size_t)gr0 * D + kc * 32 + quad * 8);
        if (gr1 < N) a1 = *(const short8*)(hin + (size_t)gr1 * D + kc * 32 + quad * 8);
        #pragma unroll
        for (int nt = 0; nt < 8; nt++) {
            short8 b = *(const short8*)(wtp + ((kc * 8 + nt) * 64 + lane) * 8);
            acc[0][nt] = __builtin_amdgcn_mfma_f32_16x16x32_bf16(a0, b, acc[0][nt], 0, 0, 0);
            acc[1][nt] = __builtin_amdgcn_mfma_f32_16x16x32_bf16(a1, b, acc[1][nt], 0, 0, 0);
        }
    }
    // z = 1,2: aggregate terms (fp8 A -> bf16, lossless)
    for (int z = 1; z < 3; z++) {
        const char* Aq = (const char*)((z == 1) ? AinQ : AoutQ);
        const short* Bz = wtp + (size_t)z * D * D;
        #pragma unroll
        for (int kc = 0; kc < 4; kc++) {
            short8 a0 = {0, 0, 0, 0, 0, 0, 0, 0};
            short8 a1 = {0, 0, 0, 0, 0, 0, 0, 0};
            if (gr0 < N) a0 = fp8row_to_bf16(*(const uint2*)(Aq + (size_t)gr0 * 128 + kc * 32 + quad * 8));
            if (gr1 < N) a1 = fp8row_to_bf16(*(const uint2*)(Aq + (size_t)gr1 * 128 + kc * 32 + quad * 8));
            #pragma unroll
            for (int nt = 0; nt < 8; nt++) {
                short8 b = *(const short8*)(Bz + ((kc * 8 + nt) * 64 + lane) * 8);
                acc[0][nt] = __builtin_amdgcn_mfma_f32_16x16x32_bf16(a0, b, acc[0][nt], 0, 0, 0);
                acc[1][nt] = __builtin_amdgcn_mfma_f32_16x16x32_bf16(a1, b, acc[1][nt], 0, 0, 0);
            }
        }
    }

    float4 bA = *(const float4*)(bcombp + r16 * 8);
    float4 bB = *(const float4*)(bcombp + r16 * 8 + 4);
    float bias[8] = {bA.x, bA.y, bA.z, bA.w, bB.x, bB.y, bB.z, bB.w};

    #pragma unroll
    for (int rt = 0; rt < 2; rt++)
        #pragma unroll
        for (int reg = 0; reg < 4; reg++) {
            int row = m0 + mrow + rt * 16 + quad * 4 + reg;
            int lrow = mrow + rt * 16 + quad * 4 + reg;
            uint4 mx = make_uint4(0, 0, 0, 0);
            if (row < N) {
                float h[8];
                short8 s8;
                #pragma unroll
                for (int nt = 0; nt < 8; nt++) {
                    h[nt] = fmaxf(acc[rt][nt][reg] + bias[nt], 0.f);
                    s8[nt] = (short)f2bf(h[nt]);
                }
                uint4 pk = *(uint4*)&s8;
                uint4 o1 = *(const uint4*)(h1b + (size_t)row * D + r16 * 8);
                uint4 o2 = *(const uint4*)(hin + (size_t)row * D + r16 * 8);
                // relu'd bf16 >= 0 -> monotone as u16; per-half 3-way max
                uint32 t0, t1, t2, t3;
                t0 = max(pk.x & 0xFFFFu, o1.x & 0xFFFFu) | max(pk.x & 0xFFFF0000u, o1.x & 0xFFFF0000u);
                t1 = max(pk.y & 0xFFFFu, o1.y & 0xFFFFu) | max(pk.y & 0xFFFF0000u, o1.y & 0xFFFF0000u);
                t2 = max(pk.z & 0xFFFFu, o1.z & 0xFFFFu) | max(pk.z & 0xFFFF0000u, o1.z & 0xFFFF0000u);
                t3 = max(pk.w & 0xFFFFu, o1.w & 0xFFFFu) | max(pk.w & 0xFFFF0000u, o1.w & 0xFFFF0000u);
                mx.x = max(t0 & 0xFFFFu, o2.x & 0xFFFFu) | max(t0 & 0xFFFF0000u, o2.x & 0xFFFF0000u);
                mx.y = max(t1 & 0xFFFFu, o2.y & 0xFFFFu) | max(t1 & 0xFFFF0000u, o2.y & 0xFFFF0000u);
                mx.z = max(t2 & 0xFFFFu, o2.z & 0xFFFFu) | max(t2 & 0xFFFF0000u, o2.z & 0xFFFF0000u);
                mx.w = max(t3 & 0xFFFFu, o2.w & 0xFFFFu) | max(t3 & 0xFFFF0000u, o2.w & 0xFFFF0000u);
            }
            *(uint4*)&Js[lrow * 136 + r16 * 8] = mx;
        }
    __syncthreads();

    float4v oacc[2][4];
    #pragma unroll
    for (int a = 0; a < 2; a++)
        #pragma unroll
        for (int b = 0; b < 4; b++)
            oacc[a][b] = (float4v){0.f, 0.f, 0.f, 0.f};

    #pragma unroll
    for (int kc = 0; kc < 4; kc++) {
        short8 a0 = *(const short8*)&Js[(mrow + r16) * 136 + kc * 32 + quad * 8];
        short8 a1 = *(const short8*)&Js[(mrow + 16 + r16) * 136 + kc * 32 + quad * 8];
        #pragma unroll
        for (int nt = 0; nt < 4; nt++) {
            short8 b = *(const short8*)(wltp + ((kc * 4 + nt) * 64 + lane) * 8);
            oacc[0][nt] = __builtin_amdgcn_mfma_f32_16x16x32_bf16(a0, b, oacc[0][nt], 0, 0, 0);
            oacc[1][nt] = __builtin_amdgcn_mfma_f32_16x16x32_bf16(a1, b, oacc[1][nt], 0, 0, 0);
        }
    }

    #pragma unroll
    for (int rt = 0; rt < 2; rt++)
        #pragma unroll
        for (int nt = 0; nt < 4; nt++)
            #pragma unroll
            for (int reg = 0; reg < 4; reg++) {
                int row = m0 + mrow + rt * 16 + quad * 4 + reg;
                int colo = nt * 16 + r16;
                if (row < N) Cout[(size_t)row * OUTD + colo] = oacc[rt][nt][reg] + blin[colo];
            }
}

// ---------------- launch ----------------

extern "C" void kernel_launch(void* const* d_in, const int* in_sizes, int n_in,
                              void* d_out, int out_size, void* d_ws, size_t ws_size,
                              hipStream_t stream) {
    const float* x     = (const float*)d_in[0];
    const int*   ei    = (const int*)d_in[1];
    const float* Wself = (const float*)d_in[2];
    const float* bself = (const float*)d_in[3];
    const float* Wstd  = (const float*)d_in[4];
    const float* bstd  = (const float*)d_in[5];
    const float* Wdts  = (const float*)d_in[6];
    const float* bdts  = (const float*)d_in[7];
    const float* Wlin  = (const float*)d_in[8];
    const float* blin  = (const float*)d_in[9];
    const float* alpha = (const float*)d_in[10];

    int N = in_sizes[0] / D;   // 50000
    int E = in_sizes[1] / 2;   // 800000
    int NBK = ceil_div(N, 128);

    char* p = (char*)d_ws;
    auto alloc = [&](size_t bytes) {
        char* q = p;
        p += (bytes + 255) & ~(size_t)255;
        return q;
    };
    int* bc    = (int*)alloc((size_t)MAXBK * 4);       // zeroed
    char* zero_end = p;
    int* off   = (int*)alloc((size_t)(MAXBK + 1) * 4);
    int* bcur  = (int*)alloc((size_t)(MAXBK + 1) * 4);
    int* rowx  = (int*)alloc((size_t)(2 * N + 8) * 4);
    uint32* ebuf = (uint32*)alloc((size_t)2 * E * 4);
    int* col   = (int*)alloc((size_t)(2 * E + 64) * 4);
    short* hb0   = (short*)alloc((size_t)N * D * 2);   // h0 = x (bf16)
    short* hb1   = (short*)alloc((size_t)N * D * 2);   // h1
    short* hb2   = (short*)alloc((size_t)N * D * 2);   // h2
    uint32* hq   = (uint32*)alloc(((size_t)N + 1) * 128);   // fp8 table + zero pad row
    uint32* AinQ  = (uint32*)alloc((size_t)N * 128);   // fp8 aggregate rows
    uint32* AoutQ = (uint32*)alloc((size_t)N * 128);
    short* wt    = (short*)alloc((size_t)9 * D * D * 2);
    short* wlt   = (short*)alloc((size_t)D * OUTD * 2);
    float* bcombp = (float*)alloc((size_t)LAYERS * D * 4);

    const int* srcp = ei;
    const int* dstp = ei + E;

    hipMemsetAsync(bc, 0, (size_t)(zero_end - (char*)bc), stream);
    hipMemsetAsync((char*)hq + (size_t)N * 128, 0, 128, stream);   // zero pad row

    int NCVX = ceil_div(N, 32);
    prep<<<BH_BLOCKS + NCVX + 11, 256, 0, stream>>>(
        srcp, dstp, E, N, NBK, NCVX, bc, x, hb0, hq,
        Wself, Wstd, Wdts, Wlin, bself, bstd, bdts, alpha, wt, wlt, bcombp);
    scan1<<<1, 1024, 0, stream>>>(bc, off, bcur, NBK);
    build<<<AP_BLOCKS, 256, 0, stream>>>(srcp, dstp, E, N, NBK, bcur, ebuf);
    bucket_count_fill<<<NBK, 256, 0, stream>>>(ebuf, off, rowx, col, N, NBK);

    int ga = ceil_div(N, 8);
    int gm = ceil_div(N, 128);

    // layer 0: agg over h0, h1 = relu(...)
    agg4<<<ga, 256, 0, stream>>>(hq, rowx, col, AinQ, AoutQ, N);
    gemm_sum<<<gm, 256, 0, stream>>>(hb0, AinQ, AoutQ, wt, bcombp, hb1, hq, N);
    // layer 1: agg over h1, h2 = relu(...)
    agg4<<<ga, 256, 0, stream>>>(hq, rowx, col, AinQ, AoutQ, N);
    gemm_sum<<<gm, 256, 0, stream>>>(hb1, AinQ, AoutQ, wt + (size_t)3 * D * D,
                                     bcombp + D, hb2, hq, N);
    // layer 2: agg over h2, h3 in-register; JK = max(h1,h2,h3); output GEMM
    agg4<<<ga, 256, 0, stream>>>(hq, rowx, col, AinQ, AoutQ, N);
    gemm_last<<<gm, 256, 0, stream>>>(hb2, AinQ, AoutQ, wt + (size_t)6 * D * D,
                                      bcombp + 2 * D, hb1, wlt, blin,
                                      (float*)d_out, N);
}

// Round 15
// 320.549 us; speedup vs baseline: 1.0312x; 1.0312x over previous
//
#include <hip/hip_runtime.h>

#define D 128
#define OUTD 64
#define LAYERS 3
#define MAXBK 512   // max buckets (node>>7); N=50000 -> 391

typedef __attribute__((ext_vector_type(8))) short short8;
typedef __attribute__((ext_vector_type(4))) float float4v;
typedef __attribute__((ext_vector_type(2))) float floatx2;
typedef unsigned int uint32;

static inline int ceil_div(int a, int b) { return (a + b - 1) / b; }

__device__ __forceinline__ unsigned short f2bf(float f) {
    unsigned int u = __float_as_uint(f);
    unsigned int r = u + 0x7FFFu + ((u >> 16) & 1u);
    return (unsigned short)(r >> 16);
}

// feature permutation: storage element position of logical feature f.
__device__ __forceinline__ int fperm(int f) { return (f & 15) * 8 + (f >> 4); }

// packed-B slot for (input storage-pos fp, output n), RT = 8 (D out) or 4 (OUTD out).
// Per-(kc,nt) 1KB lane-major block: a wave's 64 lanes read 1KB contiguous (L2-hot).
__device__ __forceinline__ int bpack(int fp, int n, int RT) {
    int kc = fp >> 5, q = (fp >> 3) & 3, j = fp & 7;
    int nt = n >> 4, r16 = n & 15;
    return (kc * RT + nt) * 512 + (q * 16 + r16) * 8 + j;
}

// ---------------- prep: bucket hist + LDS-staged x->bf16/fp8 + weight pack ----------------

#define BH_BLOCKS  64

__global__ __launch_bounds__(256)
void prep(const int* __restrict__ src, const int* __restrict__ dst, int E, int N, int NBK,
          int NCVX, int* bc,
          const float* __restrict__ x, short* __restrict__ hb, uint32* __restrict__ hq,
          const float* __restrict__ Wself, const float* __restrict__ Wstd,
          const float* __restrict__ Wdts, const float* __restrict__ Wlin,
          const float* __restrict__ bself, const float* __restrict__ bstd,
          const float* __restrict__ bdts, const float* __restrict__ alpha_p,
          short* __restrict__ wt, short* __restrict__ wlt, float* __restrict__ bcombp) {
    int b = blockIdx.x;
    if (b < BH_BLOCKS) {
        // combined per-bucket record counts (in + out records land in dest/src node buckets)
        __shared__ int bh[MAXBK];
        for (int i = threadIdx.x; i < MAXBK; i += 256) bh[i] = 0;
        __syncthreads();
        int per = (E + BH_BLOCKS - 1) / BH_BLOCKS;
        int lo = b * per, hi = min(E, lo + per);
        for (int e = lo + threadIdx.x; e < hi; e += 256) {
            int s = src[e], d = dst[e];
            atomicAdd(&bh[d >> 7], 1);
            atomicAdd(&bh[s >> 7], 1);
        }
        __syncthreads();
        for (int i = threadIdx.x; i < NBK; i += 256) {
            if (bh[i]) atomicAdd(&bc[i], bh[i]);
        }
    } else if (b < BH_BLOCKS + NCVX) {
        // LDS-staged convert: 32 nodes/block, coalesced float4 reads of x
        __shared__ float xs[32][132];
        int nb = (b - BH_BLOCKS) * 32;
        #pragma unroll
        for (int j = 0; j < 4; j++) {
            int f4 = threadIdx.x + j * 256;      // 0..1023 float4 slots
            int row = f4 >> 5, c4 = f4 & 31;
            float4 v = make_float4(0.f, 0.f, 0.f, 0.f);
            if (nb + row < N) v = *(const float4*)(x + (size_t)(nb + row) * D + c4 * 4);
            *(float4*)&xs[row][c4 * 4] = v;
        }
        __syncthreads();
        #pragma unroll
        for (int j = 0; j < 2; j++) {
            int ch = threadIdx.x + j * 256;      // 0..511 (node, q) chunks
            int r = ch >> 4, q = ch & 15;
            int n = nb + r;
            if (n < N) {
                float v[8];
                short8 s;
                #pragma unroll
                for (int fh = 0; fh < 8; fh++) {
                    float f = xs[r][q + fh * 16];
                    v[fh] = f;
                    s[fh] = (short)f2bf(f);
                }
                *(short8*)(hb + (size_t)n * D + q * 8) = s;
                uint32 u0 = __builtin_amdgcn_cvt_pk_fp8_f32(v[0], v[1], 0, false);
                u0 = __builtin_amdgcn_cvt_pk_fp8_f32(v[2], v[3], u0, true);
                uint32 u1 = __builtin_amdgcn_cvt_pk_fp8_f32(v[4], v[5], 0, false);
                u1 = __builtin_amdgcn_cvt_pk_fp8_f32(v[6], v[7], u1, true);
                *(uint2*)((char*)hq + (size_t)n * 128 + q * 8) = make_uint2(u0, u1);
            }
        }
    } else {
        int cb = b - BH_BLOCKS - NCVX;   // 0..10
        if (cb < 9) {
            int l = cb / 3, m = cb % 3;
            float a = alpha_p[0];
            float sc = (m == 0) ? 1.0f : ((m == 1) ? (1.0f - a) : a);
            const float* W = (m == 0 ? Wself : (m == 1 ? Wstd : Wdts)) + (size_t)l * D * D;
            short* o = wt + (size_t)cb * D * D;
            for (int idx = threadIdx.x; idx < D * D; idx += 256) {
                int k = idx >> 7, n = idx & 127;   // W[k][n]: input k -> output n
                o[bpack(fperm(k), n, 8)] = (short)f2bf(W[idx] * sc);
            }
        } else if (cb == 9) {
            for (int idx = threadIdx.x; idx < D * OUTD; idx += 256) {
                int k = idx >> 6, n = idx & 63;
                wlt[bpack(fperm(k), n, 4)] = (short)f2bf(Wlin[idx]);
            }
        } else {
            float a = alpha_p[0];
            for (int i = threadIdx.x; i < LAYERS * D; i += 256) {
                int l = i >> 7, j = i & 127;
                bcombp[l * D + fperm(j)] = bself[i] + (1.0f - a) * bstd[i] + a * bdts[i];
            }
        }
    }
}

// ---------------- scan over NBK buckets ----------------

__global__ __launch_bounds__(1024)
void scan1(const int* __restrict__ bc, int* __restrict__ off, int* __restrict__ bcur, int n) {
    __shared__ int wsum[16];
    __shared__ int total;
    int tid = threadIdx.x, lane = tid & 63, w = tid >> 6;
    int v = (tid < n) ? bc[tid] : 0;
    int x = v;
    #pragma unroll
    for (int o = 1; o < 64; o <<= 1) {
        int y = __shfl_up(x, o, 64);
        if (lane >= o) x += y;
    }
    if (lane == 63) wsum[w] = x;
    __syncthreads();
    if (w == 0 && lane < 16) {
        int s = wsum[lane];
        #pragma unroll
        for (int o = 1; o < 16; o <<= 1) {
            int y = __shfl_up(s, o, 16);
            if (lane >= o) s += y;
        }
        wsum[lane] = s;
        if (lane == 15) total = s;
    }
    __syncthreads();
    int wpre = w ? wsum[w - 1] : 0;
    if (tid < n) {
        int e = wpre + x - v;
        off[tid] = e;
        bcur[tid] = e;
    }
    if (tid == 0) off[n] = total;
}

// ---------------- build: binned edge append (combined records) ----------------
// record = payload << 7 | (node & 127); payload = src (in-edge) or dst + N (out-edge).

#define AP_BLOCKS 128

__global__ __launch_bounds__(256)
void build(const int* __restrict__ src, const int* __restrict__ dst, int E, int N,
           int NBK, int* bcur, uint32* __restrict__ ebuf) {
    __shared__ int h[MAXBK];
    int b = blockIdx.x;
    for (int i = threadIdx.x; i < MAXBK; i += 256) h[i] = 0;
    __syncthreads();
    int per = (E + AP_BLOCKS - 1) / AP_BLOCKS;
    int lo = b * per, hi = min(E, lo + per);
    for (int e = lo + threadIdx.x; e < hi; e += 256) {
        int s = src[e], d = dst[e];
        atomicAdd(&h[d >> 7], 1);
        atomicAdd(&h[s >> 7], 1);
    }
    __syncthreads();
    for (int i = threadIdx.x; i < NBK; i += 256) {
        int c = h[i];
        h[i] = c ? atomicAdd(&bcur[i], c) : 0;
    }
    __syncthreads();
    for (int e = lo + threadIdx.x; e < hi; e += 256) {
        int s = src[e], d = dst[e];
        int p = atomicAdd(&h[d >> 7], 1);
        ebuf[p] = ((uint32)s << 7) | (uint32)(d & 127);
        int q = atomicAdd(&h[s >> 7], 1);
        ebuf[q] = ((uint32)(d + N) << 7) | (uint32)(s & 127);
    }
}

// ---------------- bucket_count_fill ----------------
// rowx[2n] = in start, rowx[2n+1] = out start, rowx[2n+2] = end.
// col stores BYTE OFFSETS (node * 128) into the single fp8 table hq.

__global__ __launch_bounds__(256)
void bucket_count_fill(const uint32* __restrict__ ebuf, const int* __restrict__ off,
                       int* __restrict__ rowx, int* __restrict__ col, int N, int NBK) {
    __shared__ int cnt[256];
    __shared__ int wsum4[4];
    __shared__ int lcur[256];
    int k = blockIdx.x;
    int nb = k << 7;
    int tid = threadIdx.x;
    cnt[tid] = 0;
    __syncthreads();
    int lo = off[k], hi = off[k + 1];
    for (int r = lo + tid; r < hi; r += 256) {
        uint32 rec = ebuf[r];
        int t = ((rec >> 7) >= (uint32)N) ? 1 : 0;
        atomicAdd(&cnt[((rec & 127u) << 1) | t], 1);
    }
    __syncthreads();
    int lane = tid & 63, w = tid >> 6;
    int v = cnt[tid];
    int x = v;
    #pragma unroll
    for (int o = 1; o < 64; o <<= 1) {
        int y = __shfl_up(x, o, 64);
        if (lane >= o) x += y;
    }
    if (lane == 63) wsum4[w] = x;
    __syncthreads();
    if (tid == 0) {
        int s = 0;
        #pragma unroll
        for (int i = 0; i < 4; i++) { int t = wsum4[i]; wsum4[i] = s; s += t; }
    }
    __syncthreads();
    int excl = lo + wsum4[w] + x - v;
    int node = nb + (tid >> 1);
    if (node < N) rowx[(node << 1) | (tid & 1)] = excl;
    lcur[tid] = excl;
    if (k == NBK - 1 && tid == 0) rowx[2 * N] = hi;
    __syncthreads();
    for (int r = lo + tid; r < hi; r += 256) {
        uint32 rec = ebuf[r];
        uint32 pay = rec >> 7;
        int t = (pay >= (uint32)N) ? 1 : 0;
        int slot = atomicAdd(&lcur[((rec & 127u) << 1) | t], 1);
        col[slot] = (int)(((pay >= (uint32)N) ? (pay - (uint32)N) : pay) << 7);
    }
}

// ---------------- agg4: 2 nodes/wave, 4 lockstep record streams ----------------
// Streams: {n0-in, n0-out, n1-in, n1-out}, iterated together: 8 col loads + 8
// gathers issue per iteration before any wait. Clamped col addressing (provably
// in-bounds); tail lanes gather the zero row. After xor-16/32 reduction every
// lane holds the full sum: lane>>4 selects which of the 4 outputs it writes.

__global__ __launch_bounds__(256)
void agg4(const uint32* __restrict__ hq,
          const int* __restrict__ rowx, const int* __restrict__ col,
          short* __restrict__ Ain, short* __restrict__ Aout, int N) {
    int wv = threadIdx.x >> 6;
    int lane = threadIdx.x & 63;
    int n0 = (blockIdx.x * 4 + wv) * 2;
    if (n0 >= N) return;
    int n1 = n0 + 1;
    int has1 = (n1 < N) ? 1 : 0;

    int4 rx = *(const int4*)(rowx + 2 * n0);   // n0 even -> 16B aligned
    int l0 = rx.x, h0 = rx.y;                  // n0 in
    int l1 = rx.y, h1 = rx.z;                  // n0 out
    int l2 = 0, h2 = 0, l3 = 0, h3 = 0;
    if (has1) { l2 = rx.z; h2 = rx.w; l3 = rx.w; h3 = rowx[2 * n0 + 4]; }

    int rgrp = lane >> 4;
    int c8 = (lane & 15) * 8;
    int ZRB = N * 128;                         // byte offset of zero row
    const char* tb = (const char*)hq;

    floatx2 A0[4], A1[4], A2[4], A3[4];        // per-stream accumulators
    #pragma unroll
    for (int j = 0; j < 4; j++) {
        A0[j] = (floatx2){0.f, 0.f};
        A1[j] = (floatx2){0.f, 0.f};
        A2[j] = (floatx2){0.f, 0.f};
        A3[j] = (floatx2){0.f, 0.f};
    }

    int len = max(max(h0 - l0, h1 - l1), max(h2 - l2, h3 - l3));
    for (int q = 0; q < len; q += 8) {
        int ea0 = l0 + q + rgrp, eb0 = ea0 + 4;
        int ea1 = l1 + q + rgrp, eb1 = ea1 + 4;
        int ea2 = l2 + q + rgrp, eb2 = ea2 + 4;
        int ea3 = l3 + q + rgrp, eb3 = ea3 + 4;
        // 8 col loads (clamped addresses: always in-bounds)
        int ca0 = col[(ea0 < h0) ? ea0 : l0];
        int cb0 = col[(eb0 < h0) ? eb0 : l0];
        int ca1 = col[(ea1 < h1) ? ea1 : l1];
        int cb1 = col[(eb1 < h1) ? eb1 : l1];
        int ca2 = col[(ea2 < h2) ? ea2 : l2];
        int cb2 = col[(eb2 < h2) ? eb2 : l2];
        int ca3 = col[(ea3 < h3) ? ea3 : l3];
        int cb3 = col[(eb3 < h3) ? eb3 : l3];
        ca0 = (ea0 < h0) ? ca0 : ZRB;  cb0 = (eb0 < h0) ? cb0 : ZRB;
        ca1 = (ea1 < h1) ? ca1 : ZRB;  cb1 = (eb1 < h1) ? cb1 : ZRB;
        ca2 = (ea2 < h2) ? ca2 : ZRB;  cb2 = (eb2 < h2) ? cb2 : ZRB;
        ca3 = (ea3 < h3) ? ca3 : ZRB;  cb3 = (eb3 < h3) ? cb3 : ZRB;
        // 8 gathers
        uint2 va0 = *(const uint2*)(tb + (ca0 + c8));
        uint2 vb0 = *(const uint2*)(tb + (cb0 + c8));
        uint2 va1 = *(const uint2*)(tb + (ca1 + c8));
        uint2 vb1 = *(const uint2*)(tb + (cb1 + c8));
        uint2 va2 = *(const uint2*)(tb + (ca2 + c8));
        uint2 vb2 = *(const uint2*)(tb + (cb2 + c8));
        uint2 va3 = *(const uint2*)(tb + (ca3 + c8));
        uint2 vb3 = *(const uint2*)(tb + (cb3 + c8));
        #define ACCUM(ACC, va, vb) \
            ACC[0] += __builtin_amdgcn_cvt_pk_f32_fp8(va.x, false); \
            ACC[1] += __builtin_amdgcn_cvt_pk_f32_fp8(va.x, true);  \
            ACC[2] += __builtin_amdgcn_cvt_pk_f32_fp8(va.y, false); \
            ACC[3] += __builtin_amdgcn_cvt_pk_f32_fp8(va.y, true);  \
            ACC[0] += __builtin_amdgcn_cvt_pk_f32_fp8(vb.x, false); \
            ACC[1] += __builtin_amdgcn_cvt_pk_f32_fp8(vb.x, true);  \
            ACC[2] += __builtin_amdgcn_cvt_pk_f32_fp8(vb.y, false); \
            ACC[3] += __builtin_amdgcn_cvt_pk_f32_fp8(vb.y, true);
        ACCUM(A0, va0, vb0)
        ACCUM(A1, va1, vb1)
        ACCUM(A2, va2, vb2)
        ACCUM(A3, va3, vb3)
        #undef ACCUM
    }

    // fold in per-stream 1/deg, then reduce across row-groups
    float s0 = 1.0f / (float)max(h0 - l0, 1);
    float s1 = 1.0f / (float)max(h1 - l1, 1);
    float s2 = 1.0f / (float)max(h2 - l2, 1);
    float s3 = 1.0f / (float)max(h3 - l3, 1);
    floatx2 w0 = {s0, s0}, w1 = {s1, s1}, w2 = {s2, s2}, w3 = {s3, s3};
    #pragma unroll
    for (int j = 0; j < 4; j++) {
        A0[j] = A0[j] * w0;
        A1[j] = A1[j] * w1;
        A2[j] = A2[j] * w2;
        A3[j] = A3[j] * w3;
    }

    #define RED(X) \
        X.x += __shfl_xor(X.x, 16, 64); X.y += __shfl_xor(X.y, 16, 64); \
        X.x += __shfl_xor(X.x, 32, 64); X.y += __shfl_xor(X.y, 32, 64);
    #pragma unroll
    for (int j = 0; j < 4; j++) { RED(A0[j]) RED(A1[j]) RED(A2[j]) RED(A3[j]) }
    #undef RED

    // lane g = lane>>4 writes stream g: 0 -> Ain[n0], 1 -> Aout[n0], 2 -> Ain[n1], 3 -> Aout[n1]
    int g = lane >> 4;
    if (g < 2 || has1) {
        floatx2 S0 = (g == 0) ? A0[0] : ((g == 1) ? A1[0] : ((g == 2) ? A2[0] : A3[0]));
        floatx2 S1 = (g == 0) ? A0[1] : ((g == 1) ? A1[1] : ((g == 2) ? A2[1] : A3[1]));
        floatx2 S2 = (g == 0) ? A0[2] : ((g == 1) ? A1[2] : ((g == 2) ? A2[2] : A3[2]));
        floatx2 S3 = (g == 0) ? A0[3] : ((g == 1) ? A1[3] : ((g == 2) ? A2[3] : A3[3]));
        uint32 p0 = (uint32)f2bf(S0.x) | ((uint32)f2bf(S0.y) << 16);
        uint32 p1 = (uint32)f2bf(S1.x) | ((uint32)f2bf(S1.y) << 16);
        uint32 p2 = (uint32)f2bf(S2.x) | ((uint32)f2bf(S2.y) << 16);
        uint32 p3 = (uint32)f2bf(S3.x) | ((uint32)f2bf(S3.y) << 16);
        int node = (g & 2) ? n1 : n0;
        short* dp = ((g & 1) ? Aout : Ain) + (size_t)node * D + c8;
        *(uint4*)dp = make_uint4(p0, p1, p2, p3);
    }
}

// ---------------- gemm_sum: hout = relu(hin@Wself + Ain@Wstd' + Aout@Wdts' + b) ----------------
// 128-node tile, 4 waves x 32 rows. A operands direct from global; B packed global
// (bpack layout, L2-hot). Writes hout (bf16, per-layer buffer) + hq (fp8 table).
// No JK running max: per-layer h buffers are kept and reduced in gemm_last.

__global__ __launch_bounds__(256)
void gemm_sum(const short* __restrict__ hin,
              const short* __restrict__ Ain, const short* __restrict__ Aout,
              const short* __restrict__ wtp, const float* __restrict__ bcombp,
              short* __restrict__ hout, uint32* __restrict__ hq, int N) {
    int tid = threadIdx.x;
    int wave = tid >> 6, lane = tid & 63;
    int quad = lane >> 4, r16 = lane & 15;
    int m0 = blockIdx.x * 128, mrow = wave * 32;
    int gr0 = m0 + mrow + r16, gr1 = gr0 + 16;

    float4v acc[2][8];
    #pragma unroll
    for (int a = 0; a < 2; a++)
        #pragma unroll
        for (int b = 0; b < 8; b++)
            acc[a][b] = (float4v){0.f, 0.f, 0.f, 0.f};

    for (int z = 0; z < 3; z++) {
        const short* A = (z == 0) ? hin : ((z == 1) ? Ain : Aout);
        const short* Bz = wtp + (size_t)z * D * D;
        #pragma unroll
        for (int kc = 0; kc < 4; kc++) {
            short8 a0 = {0, 0, 0, 0, 0, 0, 0, 0};
            short8 a1 = {0, 0, 0, 0, 0, 0, 0, 0};
            if (gr0 < N) a0 = *(const short8*)(A + (size_t)gr0 * D + kc * 32 + quad * 8);
            if (gr1 < N) a1 = *(const short8*)(A + (size_t)gr1 * D + kc * 32 + quad * 8);
            #pragma unroll
            for (int nt = 0; nt < 8; nt++) {
                short8 b = *(const short8*)(Bz + ((kc * 8 + nt) * 64 + lane) * 8);
                acc[0][nt] = __builtin_amdgcn_mfma_f32_16x16x32_bf16(a0, b, acc[0][nt], 0, 0, 0);
                acc[1][nt] = __builtin_amdgcn_mfma_f32_16x16x32_bf16(a1, b, acc[1][nt], 0, 0, 0);
            }
        }
    }

    float4 bA = *(const float4*)(bcombp + r16 * 8);
    float4 bB = *(const float4*)(bcombp + r16 * 8 + 4);
    float bias[8] = {bA.x, bA.y, bA.z, bA.w, bB.x, bB.y, bB.z, bB.w};

    #pragma unroll
    for (int rt = 0; rt < 2; rt++)
        #pragma unroll
        for (int reg = 0; reg < 4; reg++) {
            int row = m0 + mrow + rt * 16 + quad * 4 + reg;
            if (row >= N) continue;
            float h[8];
            short8 s8;
            #pragma unroll
            for (int nt = 0; nt < 8; nt++) {
                h[nt] = fmaxf(acc[rt][nt][reg] + bias[nt], 0.f);
                s8[nt] = (short)f2bf(h[nt]);
            }
            *(short8*)(hout + (size_t)row * D + r16 * 8) = s8;
            uint32 u0 = __builtin_amdgcn_cvt_pk_fp8_f32(h[0], h[1], 0, false);
            u0 = __builtin_amdgcn_cvt_pk_fp8_f32(h[2], h[3], u0, true);
            uint32 u1 = __builtin_amdgcn_cvt_pk_fp8_f32(h[4], h[5], 0, false);
            u1 = __builtin_amdgcn_cvt_pk_fp8_f32(h[6], h[7], u1, true);
            *(uint2*)((char*)hq + (size_t)row * 128 + r16 * 8) = make_uint2(u0, u1);
        }
}

// ---------------- gemm_last: layer-2 sum-GEMM + relu + 3-way JK-max + output GEMM ----------------
// JK = max(h1, h2, h3): h3 computed in-register; h1 read from its buffer; h2 = hin
// (same buffer as the A-operand reads -> L1/L2-hot re-read, ~no extra HBM).

__global__ __launch_bounds__(256)
void gemm_last(const short* __restrict__ hin,          // h2 state (layer-2 input)
               const short* __restrict__ Ain, const short* __restrict__ Aout,
               const short* __restrict__ wtp, const float* __restrict__ bcombp,
               const short* __restrict__ h1b,          // h1 buffer
               const short* __restrict__ wltp, const float* __restrict__ blin,
               float* __restrict__ Cout, int N) {
    __shared__ __align__(16) short Js[128 * 136];
    int tid = threadIdx.x;
    int wave = tid >> 6, lane = tid & 63;
    int quad = lane >> 4, r16 = lane & 15;
    int m0 = blockIdx.x * 128, mrow = wave * 32;
    int gr0 = m0 + mrow + r16, gr1 = gr0 + 16;

    float4v acc[2][8];
    #pragma unroll
    for (int a = 0; a < 2; a++)
        #pragma unroll
        for (int b = 0; b < 8; b++)
            acc[a][b] = (float4v){0.f, 0.f, 0.f, 0.f};

    for (int z = 0; z < 3; z++) {
        const short* A = (z == 0) ? hin : ((z == 1) ? Ain : Aout);
        const short* Bz = wtp + (size_t)z * D * D;
        #pragma unroll
        for (int kc = 0; kc < 4; kc++) {
            short8 a0 = {0, 0, 0, 0, 0, 0, 0, 0};
            short8 a1 = {0, 0, 0, 0, 0, 0, 0, 0};
            if (gr0 < N) a0 = *(const short8*)(A + (size_t)gr0 * D + kc * 32 + quad * 8);
            if (gr1 < N) a1 = *(const short8*)(A + (size_t)gr1 * D + kc * 32 + quad * 8);
            #pragma unroll
            for (int nt = 0; nt < 8; nt++) {
                short8 b = *(const short8*)(Bz + ((kc * 8 + nt) * 64 + lane) * 8);
                acc[0][nt] = __builtin_amdgcn_mfma_f32_16x16x32_bf16(a0, b, acc[0][nt], 0, 0, 0);
                acc[1][nt] = __builtin_amdgcn_mfma_f32_16x16x32_bf16(a1, b, acc[1][nt], 0, 0, 0);
            }
        }
    }

    float4 bA = *(const float4*)(bcombp + r16 * 8);
    float4 bB = *(const float4*)(bcombp + r16 * 8 + 4);
    float bias[8] = {bA.x, bA.y, bA.z, bA.w, bB.x, bB.y, bB.z, bB.w};

    #pragma unroll
    for (int rt = 0; rt < 2; rt++)
        #pragma unroll
        for (int reg = 0; reg < 4; reg++) {
            int row = m0 + mrow + rt * 16 + quad * 4 + reg;
            int lrow = mrow + rt * 16 + quad * 4 + reg;
            uint4 mx = make_uint4(0, 0, 0, 0);
            if (row < N) {
                float h[8];
                short8 s8;
                #pragma unroll
                for (int nt = 0; nt < 8; nt++) {
                    h[nt] = fmaxf(acc[rt][nt][reg] + bias[nt], 0.f);
                    s8[nt] = (short)f2bf(h[nt]);
                }
                uint4 pk = *(uint4*)&s8;
                uint4 o1 = *(const uint4*)(h1b + (size_t)row * D + r16 * 8);
                uint4 o2 = *(const uint4*)(hin + (size_t)row * D + r16 * 8);
                // relu'd bf16 >= 0 -> monotone as u16; per-half 3-way max
                uint32 t0, t1, t2, t3;
                t0 = max(pk.x & 0xFFFFu, o1.x & 0xFFFFu) | max(pk.x & 0xFFFF0000u, o1.x & 0xFFFF0000u);
                t1 = max(pk.y & 0xFFFFu, o1.y & 0xFFFFu) | max(pk.y & 0xFFFF0000u, o1.y & 0xFFFF0000u);
                t2 = max(pk.z & 0xFFFFu, o1.z & 0xFFFFu) | max(pk.z & 0xFFFF0000u, o1.z & 0xFFFF0000u);
                t3 = max(pk.w & 0xFFFFu, o1.w & 0xFFFFu) | max(pk.w & 0xFFFF0000u, o1.w & 0xFFFF0000u);
                mx.x = max(t0 & 0xFFFFu, o2.x & 0xFFFFu) | max(t0 & 0xFFFF0000u, o2.x & 0xFFFF0000u);
                mx.y = max(t1 & 0xFFFFu, o2.y & 0xFFFFu) | max(t1 & 0xFFFF0000u, o2.y & 0xFFFF0000u);
                mx.z = max(t2 & 0xFFFFu, o2.z & 0xFFFFu) | max(t2 & 0xFFFF0000u, o2.z & 0xFFFF0000u);
                mx.w = max(t3 & 0xFFFFu, o2.w & 0xFFFFu) | max(t3 & 0xFFFF0000u, o2.w & 0xFFFF0000u);
            }
            *(uint4*)&Js[lrow * 136 + r16 * 8] = mx;
        }
    __syncthreads();

    float4v oacc[2][4];
    #pragma unroll
    for (int a = 0; a < 2; a++)
        #pragma unroll
        for (int b = 0; b < 4; b++)
            oacc[a][b] = (float4v){0.f, 0.f, 0.f, 0.f};

    #pragma unroll
    for (int kc = 0; kc < 4; kc++) {
        short8 a0 = *(const short8*)&Js[(mrow + r16) * 136 + kc * 32 + quad * 8];
        short8 a1 = *(const short8*)&Js[(mrow + 16 + r16) * 136 + kc * 32 + quad * 8];
        #pragma unroll
        for (int nt = 0; nt < 4; nt++) {
            short8 b = *(const short8*)(wltp + ((kc * 4 + nt) * 64 + lane) * 8);
            oacc[0][nt] = __builtin_amdgcn_mfma_f32_16x16x32_bf16(a0, b, oacc[0][nt], 0, 0, 0);
            oacc[1][nt] = __builtin_amdgcn_mfma_f32_16x16x32_bf16(a1, b, oacc[1][nt], 0, 0, 0);
        }
    }

    #pragma unroll
    for (int rt = 0; rt < 2; rt++)
        #pragma unroll
        for (int nt = 0; nt < 4; nt++)
            #pragma unroll
            for (int reg = 0; reg < 4; reg++) {
                int row = m0 + mrow + rt * 16 + quad * 4 + reg;
                int colo = nt * 16 + r16;
                if (row < N) Cout[(size_t)row * OUTD + colo] = oacc[rt][nt][reg] + blin[colo];
            }
}

// ---------------- launch ----------------

extern "C" void kernel_launch(void* const* d_in, const int* in_sizes, int n_in,
                              void* d_out, int out_size, void* d_ws, size_t ws_size,
                              hipStream_t stream) {
    const float* x     = (const float*)d_in[0];
    const int*   ei    = (const int*)d_in[1];
    const float* Wself = (const float*)d_in[2];
    const float* bself = (const float*)d_in[3];
    const float* Wstd  = (const float*)d_in[4];
    const float* bstd  = (const float*)d_in[5];
    const float* Wdts  = (const float*)d_in[6];
    const float* bdts  = (const float*)d_in[7];
    const float* Wlin  = (const float*)d_in[8];
    const float* blin  = (const float*)d_in[9];
    const float* alpha = (const float*)d_in[10];

    int N = in_sizes[0] / D;   // 50000
    int E = in_sizes[1] / 2;   // 800000
    int NBK = ceil_div(N, 128);

    char* p = (char*)d_ws;
    auto alloc = [&](size_t bytes) {
        char* q = p;
        p += (bytes + 255) & ~(size_t)255;
        return q;
    };
    int* bc    = (int*)alloc((size_t)MAXBK * 4);       // zeroed
    char* zero_end = p;
    int* off   = (int*)alloc((size_t)(MAXBK + 1) * 4);
    int* bcur  = (int*)alloc((size_t)(MAXBK + 1) * 4);
    int* rowx  = (int*)alloc((size_t)(2 * N + 8) * 4);
    uint32* ebuf = (uint32*)alloc((size_t)2 * E * 4);
    int* col   = (int*)alloc((size_t)(2 * E + 64) * 4);
    short* hb0   = (short*)alloc((size_t)N * D * 2);   // h0 = x (bf16)
    short* hb1   = (short*)alloc((size_t)N * D * 2);   // h1
    short* hb2   = (short*)alloc((size_t)N * D * 2);   // h2
    uint32* hq   = (uint32*)alloc(((size_t)N + 1) * 128);   // fp8 table + zero pad row
    short* Ain   = (short*)alloc((size_t)N * D * 2);
    short* Aout  = (short*)alloc((size_t)N * D * 2);
    short* wt    = (short*)alloc((size_t)9 * D * D * 2);
    short* wlt   = (short*)alloc((size_t)D * OUTD * 2);
    float* bcombp = (float*)alloc((size_t)LAYERS * D * 4);

    const int* srcp = ei;
    const int* dstp = ei + E;

    hipMemsetAsync(bc, 0, (size_t)(zero_end - (char*)bc), stream);
    hipMemsetAsync((char*)hq + (size_t)N * 128, 0, 128, stream);   // zero pad row

    int NCVX = ceil_div(N, 32);
    prep<<<BH_BLOCKS + NCVX + 11, 256, 0, stream>>>(
        srcp, dstp, E, N, NBK, NCVX, bc, x, hb0, hq,
        Wself, Wstd, Wdts, Wlin, bself, bstd, bdts, alpha, wt, wlt, bcombp);
    scan1<<<1, 1024, 0, stream>>>(bc, off, bcur, NBK);
    build<<<AP_BLOCKS, 256, 0, stream>>>(srcp, dstp, E, N, NBK, bcur, ebuf);
    bucket_count_fill<<<NBK, 256, 0, stream>>>(ebuf, off, rowx, col, N, NBK);

    int ga = ceil_div(N, 8);
    int gm = ceil_div(N, 128);

    // layer 0: agg over h0, h1 = relu(...)
    agg4<<<ga, 256, 0, stream>>>(hq, rowx, col, Ain, Aout, N);
    gemm_sum<<<gm, 256, 0, stream>>>(hb0, Ain, Aout, wt, bcombp, hb1, hq, N);
    // layer 1: agg over h1, h2 = relu(...)
    agg4<<<ga, 256, 0, stream>>>(hq, rowx, col, Ain, Aout, N);
    gemm_sum<<<gm, 256, 0, stream>>>(hb1, Ain, Aout, wt + (size_t)3 * D * D,
                                     bcombp + D, hb2, hq, N);
    // layer 2: agg over h2, h3 in-register; JK = max(h1,h2,h3); output GEMM
    agg4<<<ga, 256, 0, stream>>>(hq, rowx, col, Ain, Aout, N);
    gemm_last<<<gm, 256, 0, stream>>>(hb2, Ain, Aout, wt + (size_t)6 * D * D,
                                      bcombp + 2 * D, hb1, wlt, blin,
                                      (float*)d_out, N);
}